// Round 2
// baseline (577.084 us; speedup 1.0000x reference)
//
#include <hip/hip_runtime.h>

// RISnetPIv2: B=128, U=16, A=1024, FEAT=4, INFO=8.
// e_u/e_a are uniform averaging matrices -> each layer's 32-ch feature tensor
// factors into 4 blocks: ll[B,U,A,8] (bf16 in ws), lg[B,U,8], gl[B,A,8],
// gg[B,8] (fp32). Skip-adds act blockwise. ll processed in-place (per-thread
// read-then-write of the same position); f1 ll skip is RECOMPUTED from the
// input channel at layer 5; only f3 ll gets a pinned bf16 copy.
// Workspace: 2*33.5MB bf16 + 16MB gl + <1MB misc ~= 81 MB.

#define NB 128
#define NU 16
#define NA 1024

static constexpr float PI_F = 3.14159265358979323846f;

__device__ __forceinline__ float wave_reduce_sum(float v) {
#pragma unroll
    for (int d = 1; d < 64; d <<= 1) v += __shfl_xor(v, d, 64);
    return v;
}

__device__ __forceinline__ unsigned short f2bf(float f) {  // RNE
    unsigned int u = __float_as_uint(f);
    u += 0x7fffu + ((u >> 16) & 1u);
    return (unsigned short)(u >> 16);
}
__device__ __forceinline__ unsigned int pack2(float a, float b) {
    return (unsigned int)f2bf(a) | ((unsigned int)f2bf(b) << 16);
}
__device__ __forceinline__ void load8(const unsigned short* p, float x[8]) {
    uint4 v = *reinterpret_cast<const uint4*>(p);
    x[0] = __uint_as_float(v.x << 16); x[1] = __uint_as_float(v.x & 0xffff0000u);
    x[2] = __uint_as_float(v.y << 16); x[3] = __uint_as_float(v.y & 0xffff0000u);
    x[4] = __uint_as_float(v.z << 16); x[5] = __uint_as_float(v.z & 0xffff0000u);
    x[6] = __uint_as_float(v.w << 16); x[7] = __uint_as_float(v.w & 0xffff0000u);
}
__device__ __forceinline__ void store8(unsigned short* p, const float x[8]) {
    uint4 v;
    v.x = pack2(x[0], x[1]); v.y = pack2(x[2], x[3]);
    v.z = pack2(x[4], x[5]); v.w = pack2(x[6], x[7]);
    *reinterpret_cast<uint4*>(p) = v;
}

// ---------------- Layer 1: input channel [B,4,U,A] ----------------
__global__ __launch_bounds__(128) void layer_first(
    const float* __restrict__ ch, const float* __restrict__ W1,
    const float* __restrict__ b1, unsigned short* __restrict__ ll_out,
    float* __restrict__ lg_sum, float* __restrict__ gl_out,
    float* __restrict__ gg_sum)
{
    const int b = blockIdx.x;
    const int a = blockIdx.y * 128 + threadIdx.x;
    const int lane = threadIdx.x & 63;

    float glacc[8], ggacc[8];
#pragma unroll
    for (int i = 0; i < 8; ++i) { glacc[i] = 0.f; ggacc[i] = 0.f; }

    for (int u = 0; u < NU; ++u) {
        float x[4];
#pragma unroll
        for (int c = 0; c < 4; ++c)
            x[c] = ch[(((size_t)b * 4 + c) * NU + u) * NA + a];

        float y[32];
#pragma unroll
        for (int o = 0; o < 32; ++o) y[o] = b1[o];
#pragma unroll
        for (int j = 0; j < 4; ++j)
#pragma unroll
            for (int c = 0; c < 4; ++c) {
                const float* wr = W1 + (j * 4 + c) * 8;
#pragma unroll
                for (int oi = 0; oi < 8; ++oi)
                    y[j * 8 + oi] = fmaf(x[c], wr[oi], y[j * 8 + oi]);
            }
#pragma unroll
        for (int o = 0; o < 32; ++o) y[o] = fmaxf(y[o], 0.f);

        const size_t xoff = (((size_t)(b * NU + u)) * NA + a) * 8;
        store8(ll_out + xoff, y);

#pragma unroll
        for (int i = 0; i < 8; ++i) glacc[i] += y[16 + i];
#pragma unroll
        for (int i = 0; i < 8; ++i) ggacc[i] += y[24 + i];

        float s[8];
#pragma unroll
        for (int i = 0; i < 8; ++i) s[i] = wave_reduce_sum(y[8 + i]);
        if (lane == 0) {
            float* lp = lg_sum + (b * NU + u) * 8;
#pragma unroll
            for (int i = 0; i < 8; ++i) atomicAdd(lp + i, s[i]);
        }
    }
    {
        const float invU = 1.f / 16.f;
        float4* gp = reinterpret_cast<float4*>(gl_out + ((size_t)b * NA + a) * 8);
        gp[0] = make_float4(glacc[0]*invU, glacc[1]*invU, glacc[2]*invU, glacc[3]*invU);
        gp[1] = make_float4(glacc[4]*invU, glacc[5]*invU, glacc[6]*invU, glacc[7]*invU);
    }
#pragma unroll
    for (int i = 0; i < 8; ++i) ggacc[i] = wave_reduce_sum(ggacc[i]);
    if (lane == 0) {
        float* gp2 = gg_sum + b * 8;
#pragma unroll
        for (int i = 0; i < 8; ++i) atomicAdd(gp2 + i, ggacc[i]);
    }
}

// -------- prep: base[b,u,32] = bias + lg·W_lg + gg·W_gg (optional input skip) ----
__global__ __launch_bounds__(256) void prep_base_k(
    const float* __restrict__ lg_sum, const float* __restrict__ lg_skip,
    const float* __restrict__ gg_sum, const float* __restrict__ gg_skip,
    const float* __restrict__ Wl, const float* __restrict__ bl,
    float* __restrict__ base)
{
    const int t = blockIdx.x * 256 + threadIdx.x;  // b*16+u
    if (t >= NB * NU) return;
    const int b = t >> 4;
    const float invA = 1.f / 1024.f, invUA = 1.f / 16384.f;
    float lg[8], gg[8];
#pragma unroll
    for (int c = 0; c < 8; ++c) {
        float v = lg_sum[t * 8 + c] * invA;
        if (lg_skip) v = (v + lg_skip[t * 8 + c] * invA) * 0.5f;
        lg[c] = v;
    }
#pragma unroll
    for (int c = 0; c < 8; ++c) {
        float v = gg_sum[b * 8 + c] * invUA;
        if (gg_skip) v = (v + gg_skip[b * 8 + c] * invUA) * 0.5f;
        gg[c] = v;
    }
    float y[32];
#pragma unroll
    for (int o = 0; o < 32; ++o) y[o] = bl[o];
#pragma unroll
    for (int j = 0; j < 4; ++j)
#pragma unroll
        for (int c = 0; c < 8; ++c) {
            const float* wl = Wl + (j * 32 + 8 + c) * 8;
            const float* wg = Wl + (j * 32 + 24 + c) * 8;
#pragma unroll
            for (int oi = 0; oi < 8; ++oi) {
                y[j * 8 + oi] = fmaf(lg[c], wl[oi], y[j * 8 + oi]);
                y[j * 8 + oi] = fmaf(gg[c], wg[oi], y[j * 8 + oi]);
            }
        }
#pragma unroll
    for (int o = 0; o < 32; ++o) base[t * 32 + o] = y[o];
}

// ---------------- Layers 2..7 main ----------------
// ll_in / ll_out may alias (in-place is safe: per-thread read-then-write of
// the same position; store value depends on the load) -> no __restrict__ there.
__global__ __launch_bounds__(128) void layer_main(
    const unsigned short* ll_in, const float* __restrict__ gl_in,
    const float* __restrict__ gl_skip, const float* __restrict__ base,
    const float* __restrict__ Wl,
    const unsigned short* __restrict__ ll_skip,          // layer 7: f3 ll
    const float* __restrict__ ch, const float* __restrict__ W1,
    const float* __restrict__ b1,                        // layer 5: recompute f1 ll
    unsigned short* ll_out, float* __restrict__ lg_sum,
    float* __restrict__ gl_out, float* __restrict__ gg_sum)
{
    const int b = blockIdx.x;
    const int a = blockIdx.y * 128 + threadIdx.x;
    const int lane = threadIdx.x & 63;

    float g[8];
    {
        const float4* gp = reinterpret_cast<const float4*>(gl_in + ((size_t)b * NA + a) * 8);
        float4 g0 = gp[0], g1 = gp[1];
        if (gl_skip) {
            const float4* sp = reinterpret_cast<const float4*>(gl_skip + ((size_t)b * NA + a) * 8);
            float4 s0 = sp[0], s1 = sp[1];
            g0.x = (g0.x + s0.x) * 0.5f; g0.y = (g0.y + s0.y) * 0.5f;
            g0.z = (g0.z + s0.z) * 0.5f; g0.w = (g0.w + s0.w) * 0.5f;
            g1.x = (g1.x + s1.x) * 0.5f; g1.y = (g1.y + s1.y) * 0.5f;
            g1.z = (g1.z + s1.z) * 0.5f; g1.w = (g1.w + s1.w) * 0.5f;
        }
        g[0]=g0.x; g[1]=g0.y; g[2]=g0.z; g[3]=g0.w;
        g[4]=g1.x; g[5]=g1.y; g[6]=g1.z; g[7]=g1.w;
    }
    float cgl[32];
#pragma unroll
    for (int o = 0; o < 32; ++o) cgl[o] = 0.f;
#pragma unroll
    for (int j = 0; j < 4; ++j)
#pragma unroll
        for (int c = 0; c < 8; ++c) {
            const float* wr = Wl + (j * 32 + 16 + c) * 8;
#pragma unroll
            for (int oi = 0; oi < 8; ++oi)
                cgl[j * 8 + oi] = fmaf(g[c], wr[oi], cgl[j * 8 + oi]);
        }

    float glacc[8], ggacc[8];
#pragma unroll
    for (int i = 0; i < 8; ++i) { glacc[i] = 0.f; ggacc[i] = 0.f; }

    for (int u = 0; u < NU; ++u) {
        const float* bp = base + (b * NU + u) * 32;  // wave-uniform
        float y[32];
#pragma unroll
        for (int o = 0; o < 32; ++o) y[o] = cgl[o] + bp[o];

        const size_t xoff = (((size_t)(b * NU + u)) * NA + a) * 8;
        float x[8];
        load8(ll_in + xoff, x);
#pragma unroll
        for (int j = 0; j < 4; ++j)
#pragma unroll
            for (int c = 0; c < 8; ++c) {
                const float* wr = Wl + (j * 32 + c) * 8;  // wave-uniform
#pragma unroll
                for (int oi = 0; oi < 8; ++oi)
                    y[j * 8 + oi] = fmaf(x[c], wr[oi], y[j * 8 + oi]);
            }
#pragma unroll
        for (int o = 0; o < 32; ++o) y[o] = fmaxf(y[o], 0.f);

        float out8[8];
#pragma unroll
        for (int i = 0; i < 8; ++i) out8[i] = y[i];
        if (ll_skip) {                       // layer 7: average with stored f3 ll
            float s[8];
            load8(ll_skip + xoff, s);
#pragma unroll
            for (int i = 0; i < 8; ++i) out8[i] = (out8[i] + s[i]) * 0.5f;
        } else if (ch) {                     // layer 5: recompute f1 ll from input
            float xc[4];
#pragma unroll
            for (int c = 0; c < 4; ++c)
                xc[c] = ch[(((size_t)b * 4 + c) * NU + u) * NA + a];
            float s[8];
#pragma unroll
            for (int i = 0; i < 8; ++i) s[i] = b1[i];
#pragma unroll
            for (int c = 0; c < 4; ++c)
#pragma unroll
                for (int i = 0; i < 8; ++i)
                    s[i] = fmaf(xc[c], W1[c * 8 + i], s[i]);
#pragma unroll
            for (int i = 0; i < 8; ++i)
                out8[i] = (out8[i] + fmaxf(s[i], 0.f)) * 0.5f;
        }
        store8(ll_out + xoff, out8);

#pragma unroll
        for (int i = 0; i < 8; ++i) glacc[i] += y[16 + i];
#pragma unroll
        for (int i = 0; i < 8; ++i) ggacc[i] += y[24 + i];

        float s[8];
#pragma unroll
        for (int i = 0; i < 8; ++i) s[i] = wave_reduce_sum(y[8 + i]);
        if (lane == 0) {
            float* lp = lg_sum + (b * NU + u) * 8;
#pragma unroll
            for (int i = 0; i < 8; ++i) atomicAdd(lp + i, s[i]);
        }
    }
    {
        const float invU = 1.f / 16.f;
        float4* gp = reinterpret_cast<float4*>(gl_out + ((size_t)b * NA + a) * 8);
        gp[0] = make_float4(glacc[0]*invU, glacc[1]*invU, glacc[2]*invU, glacc[3]*invU);
        gp[1] = make_float4(glacc[4]*invU, glacc[5]*invU, glacc[6]*invU, glacc[7]*invU);
    }
#pragma unroll
    for (int i = 0; i < 8; ++i) ggacc[i] = wave_reduce_sum(ggacc[i]);
    if (lane == 0) {
        float* gp2 = gg_sum + b * 8;
#pragma unroll
        for (int i = 0; i < 8; ++i) atomicAdd(gp2 + i, ggacc[i]);
    }
}

// ---------------- Layer 8: out[b,a] = pi * (mean_u f·W8 + b8) ----------------
__global__ __launch_bounds__(128) void layer_out(
    const unsigned short* __restrict__ ll,   // f7' ll (skip already applied)
    const float* __restrict__ lg7, const float* __restrict__ lg3,  // raw sums
    const float* __restrict__ gl7, const float* __restrict__ gl3,  // means
    const float* __restrict__ gg7, const float* __restrict__ gg3,  // raw sums
    const float* __restrict__ W8, const float* __restrict__ b8,
    float* __restrict__ out)
{
    const int b = blockIdx.x;
    const int a = blockIdx.y * 128 + threadIdx.x;
    const float invA = 1.f / 1024.f, invUA = 1.f / 16384.f, invU = 1.f / 16.f;

    float sb = b8[0];
#pragma unroll
    for (int c = 0; c < 8; ++c) {
        float s7 = 0.f, s3 = 0.f;
#pragma unroll
        for (int u = 0; u < NU; ++u) {
            s7 += lg7[(b * NU + u) * 8 + c];
            s3 += lg3[(b * NU + u) * 8 + c];
        }
        sb += ((s7 * invA + s3 * invA) * 0.5f * invU) * W8[8 + c];
    }
#pragma unroll
    for (int c = 0; c < 8; ++c)
        sb += ((gg7[b * 8 + c] + gg3[b * 8 + c]) * invUA * 0.5f) * W8[24 + c];

    float acc = 0.f;
    for (int u = 0; u < NU; ++u) {
        float x[8];
        load8(ll + (((size_t)(b * NU + u)) * NA + a) * 8, x);
#pragma unroll
        for (int c = 0; c < 8; ++c) acc += x[c] * W8[c];
    }
    acc *= invU;
    {
        const float4* g7 = reinterpret_cast<const float4*>(gl7 + ((size_t)b * NA + a) * 8);
        const float4* g3 = reinterpret_cast<const float4*>(gl3 + ((size_t)b * NA + a) * 8);
        float4 a0 = g7[0], a1 = g7[1], b0 = g3[0], b1v = g3[1];
        acc += 0.5f * (a0.x + b0.x) * W8[16] + 0.5f * (a0.y + b0.y) * W8[17]
             + 0.5f * (a0.z + b0.z) * W8[18] + 0.5f * (a0.w + b0.w) * W8[19]
             + 0.5f * (a1.x + b1v.x) * W8[20] + 0.5f * (a1.y + b1v.y) * W8[21]
             + 0.5f * (a1.z + b1v.z) * W8[22] + 0.5f * (a1.w + b1v.w) * W8[23];
    }
    out[(size_t)b * NA + a] = (acc + sb) * PI_F;
}

extern "C" void kernel_launch(void* const* d_in, const int* in_sizes, int n_in,
                              void* d_out, int out_size, void* d_ws, size_t ws_size,
                              hipStream_t stream) {
    const float* channel = (const float*)d_in[0];
    const float* W1 = (const float*)d_in[1];
    const float* b1 = (const float*)d_in[2];
    const float* Wm = (const float*)d_in[3];
    const float* bm = (const float*)d_in[4];
    const float* W8 = (const float*)d_in[5];
    const float* b8 = (const float*)d_in[6];

    const size_t LL = (size_t)NB * NU * NA * 8;  // 16,777,216 elems
    const size_t GL = (size_t)NB * NA * 8;       // 1,048,576
    const size_t LG = (size_t)NB * NU * 8;       // 16,384
    const size_t GG = (size_t)NB * 8;            // 1,024

    unsigned short* cur = (unsigned short*)d_ws;        // bf16, 33.5 MB
    unsigned short* f3s = cur + LL;                     // bf16, 33.5 MB
    float* glb = (float*)(f3s + LL);                    // 4 x GL fp32, 16 MB
    float* g0 = glb, *g1 = glb + GL, *g2 = glb + 2 * GL, *g3 = glb + 3 * GL;
    float* lgb = glb + 4 * GL;                          // 7 x LG
    float* ggb = lgb + 7 * LG;                          // 7 x GG
    float* base = ggb + 7 * GG;                         // 2048 x 32

    // zero atomic-sum buffers (lg + gg contiguous)
    hipMemsetAsync(lgb, 0, (7 * LG + 7 * GG) * sizeof(float), stream);

    dim3 grid(NB, NA / 128), blk(128);

    // L1: f1 -> cur, g0, lgb0, ggb0
    layer_first<<<grid, blk, 0, stream>>>(channel, W1, b1, cur, lgb, g0, ggb);

    // L2: cur -> cur (in-place), g0 -> g2
    prep_base_k<<<8, 256, 0, stream>>>(lgb, nullptr, ggb, nullptr,
                                       Wm, bm, base);
    layer_main<<<grid, blk, 0, stream>>>(cur, g0, nullptr, base, Wm,
        nullptr, nullptr, nullptr, nullptr,
        cur, lgb + 1 * LG, g2, ggb + 1 * GG);

    // L3: cur -> f3s (pinned f3 copy), g2 -> g1
    prep_base_k<<<8, 256, 0, stream>>>(lgb + 1 * LG, nullptr, ggb + 1 * GG, nullptr,
                                       Wm + 1024, bm + 32, base);
    layer_main<<<grid, blk, 0, stream>>>(cur, g2, nullptr, base, Wm + 1024,
        nullptr, nullptr, nullptr, nullptr,
        f3s, lgb + 2 * LG, g1, ggb + 2 * GG);

    // L4: f3s -> cur, g1 -> g3
    prep_base_k<<<8, 256, 0, stream>>>(lgb + 2 * LG, nullptr, ggb + 2 * GG, nullptr,
                                       Wm + 2048, bm + 64, base);
    layer_main<<<grid, blk, 0, stream>>>(f3s, g1, nullptr, base, Wm + 2048,
        nullptr, nullptr, nullptr, nullptr,
        cur, lgb + 3 * LG, g3, ggb + 3 * GG);

    // L5: cur -> cur, g3 -> g2; ll-skip = recomputed f1 from channel
    prep_base_k<<<8, 256, 0, stream>>>(lgb + 3 * LG, nullptr, ggb + 3 * GG, nullptr,
                                       Wm + 3072, bm + 96, base);
    layer_main<<<grid, blk, 0, stream>>>(cur, g3, nullptr, base, Wm + 3072,
        nullptr, channel, W1, b1,
        cur, lgb + 4 * LG, g2, ggb + 4 * GG);

    // L6: cur -> cur, g2 -> g3; input-side skip with f1 factors (lgb0/ggb0/g0)
    prep_base_k<<<8, 256, 0, stream>>>(lgb + 4 * LG, lgb, ggb + 4 * GG, ggb,
                                       Wm + 4096, bm + 128, base);
    layer_main<<<grid, blk, 0, stream>>>(cur, g2, g0, base, Wm + 4096,
        nullptr, nullptr, nullptr, nullptr,
        cur, lgb + 5 * LG, g3, ggb + 5 * GG);

    // L7: cur -> cur, g3 -> g2; ll-skip = f3s
    prep_base_k<<<8, 256, 0, stream>>>(lgb + 5 * LG, nullptr, ggb + 5 * GG, nullptr,
                                       Wm + 5120, bm + 160, base);
    layer_main<<<grid, blk, 0, stream>>>(cur, g3, nullptr, base, Wm + 5120,
        f3s, nullptr, nullptr, nullptr,
        cur, lgb + 6 * LG, g2, ggb + 6 * GG);

    // L8
    layer_out<<<grid, blk, 0, stream>>>(cur, lgb + 6 * LG, lgb + 2 * LG,
                                        g2, g1, ggb + 6 * GG, ggb + 2 * GG,
                                        W8, b8, (float*)d_out);
}